// Round 8
// baseline (597.040 us; speedup 1.0000x reference)
//
#include <hip/hip_runtime.h>
#include <cstdint>
#include <cstddef>

#define N_NODES 100000
#define E_EDGES 1600000
#define HCH 128
#define NHEADS 8
#define HDIM 16

typedef unsigned int uint;
typedef unsigned short ushort;
typedef unsigned char uchar;
typedef __attribute__((ext_vector_type(8))) short short8;
typedef __attribute__((ext_vector_type(4))) float floatx4;
typedef __attribute__((ext_vector_type(2))) float floatx2;

__device__ __forceinline__ ushort f2bf(float f) {
    uint u = __float_as_uint(f);
    u = (u + 0x7fff + ((u >> 16) & 1)) >> 16;
    return (ushort)u;
}
__device__ __forceinline__ float bflo(uint p) { return __uint_as_float(p << 16); }
__device__ __forceinline__ float bfhi(uint p) { return __uint_as_float(p & 0xffff0000u); }

// ================= MFMA GEMMs =================
#define LDSPAD 8
#define SMEM_BYTES (17408 + 34816)

// q -> bf16 rows; k,v -> fp8 e4m3 interleaved records kv[node] = {k[128], v[128]} (256 B)
__global__ __launch_bounds__(256) void gemm_qkv(
    const float* __restrict__ A,
    const float* __restrict__ Wq, const float* __restrict__ Wk, const float* __restrict__ Wv,
    const float* __restrict__ bq, const float* __restrict__ bk, const float* __restrict__ bv,
    ushort* __restrict__ qo, uchar* __restrict__ kv,
    int M)
{
    __shared__ __align__(16) char smem[SMEM_BYTES];
    ushort (*As)[HCH + LDSPAD] = (ushort(*)[HCH + LDSPAD])smem;
    ushort (*Wt)[HCH + LDSPAD] = (ushort(*)[HCH + LDSPAD])(smem + 17408);
    float (*Cs)[132] = (float(*)[132])(smem + 17408);

    const int t = threadIdx.x;
    const int mb = blockIdx.x * 64;
    const float* W;
    const float* bias;
    if (blockIdx.y == 0)      { W = Wq; bias = bq; }
    else if (blockIdx.y == 1) { W = Wk; bias = bk; }
    else                      { W = Wv; bias = bv; }

#pragma unroll
    for (int i = 0; i < 8; i++) {
        int p = t + i * 256;
        int row = p >> 5, c4 = p & 31;
        int g = mb + row;
        float4 a4 = make_float4(0.f, 0.f, 0.f, 0.f);
        if (g < M) a4 = *(const float4*)(A + (size_t)g * HCH + c4 * 4);
        uint lo = (uint)f2bf(a4.x) | ((uint)f2bf(a4.y) << 16);
        uint hi = (uint)f2bf(a4.z) | ((uint)f2bf(a4.w) << 16);
        *(uint2*)(&As[row][c4 * 4]) = make_uint2(lo, hi);
    }
#pragma unroll
    for (int i = 0; i < 16; i++) {
        int p = t + i * 256;
        int n = p & 127, k4 = p >> 7;
        float w0 = W[(size_t)(k4 * 4 + 0) * HCH + n];
        float w1 = W[(size_t)(k4 * 4 + 1) * HCH + n];
        float w2 = W[(size_t)(k4 * 4 + 2) * HCH + n];
        float w3 = W[(size_t)(k4 * 4 + 3) * HCH + n];
        uint lo = (uint)f2bf(w0) | ((uint)f2bf(w1) << 16);
        uint hi = (uint)f2bf(w2) | ((uint)f2bf(w3) << 16);
        *(uint2*)(&Wt[n][k4 * 4]) = make_uint2(lo, hi);
    }
    __syncthreads();

    const int lane = t & 63;
    const int w = t >> 6;
    const int m_l = lane & 15;
    const int q_l = lane >> 4;

    floatx4 acc[8];
#pragma unroll
    for (int tl = 0; tl < 8; tl++) acc[tl] = (floatx4){0.f, 0.f, 0.f, 0.f};

#pragma unroll
    for (int ks = 0; ks < HCH; ks += 32) {
        short8 af = *(const short8*)(&As[w * 16 + m_l][ks + q_l * 8]);
#pragma unroll
        for (int tl = 0; tl < 8; tl++) {
            short8 bf = *(const short8*)(&Wt[tl * 16 + m_l][ks + q_l * 8]);
            acc[tl] = __builtin_amdgcn_mfma_f32_16x16x32_bf16(af, bf, acc[tl], 0, 0, 0);
        }
    }
    __syncthreads();

#pragma unroll
    for (int tl = 0; tl < 8; tl++)
#pragma unroll
        for (int r = 0; r < 4; r++)
            Cs[w * 16 + q_l * 4 + r][tl * 16 + m_l] = acc[tl][r];
    __syncthreads();

#pragma unroll
    for (int i = 0; i < 8; i++) {
        int p = t + i * 256;
        int row = p >> 5, c4 = p & 31;
        int g = mb + row;
        if (g >= M) continue;
        float4 b4 = *(const float4*)(bias + c4 * 4);
        float v0 = Cs[row][c4 * 4 + 0] + b4.x;
        float v1 = Cs[row][c4 * 4 + 1] + b4.y;
        float v2 = Cs[row][c4 * 4 + 2] + b4.z;
        float v3 = Cs[row][c4 * 4 + 3] + b4.w;
        if (blockIdx.y == 0) {
            uint lo = (uint)f2bf(v0) | ((uint)f2bf(v1) << 16);
            uint hi = (uint)f2bf(v2) | ((uint)f2bf(v3) << 16);
            *(uint2*)(qo + (size_t)g * HCH + c4 * 4) = make_uint2(lo, hi);
        } else {
            int pk = __builtin_amdgcn_cvt_pk_fp8_f32(v0, v1, 0, false);
            pk = __builtin_amdgcn_cvt_pk_fp8_f32(v2, v3, pk, true);
            uchar* outp = kv + (size_t)g * 256 + (blockIdx.y == 2 ? 128 : 0);
            *(uint*)(outp + c4 * 4) = (uint)pk;
        }
    }
}

// out = x + (attended_bf16_unnorm * (1/L[head])) @ Wo + bo
__global__ __launch_bounds__(256) void gemm_out(
    const ushort* __restrict__ A, const float* __restrict__ W,
    const float* __restrict__ bias, const float* __restrict__ res,
    const float* __restrict__ head_l,
    float* __restrict__ C, int M)
{
    __shared__ __align__(16) char smem[SMEM_BYTES];
    ushort (*As)[HCH + LDSPAD] = (ushort(*)[HCH + LDSPAD])smem;
    ushort (*Wt)[HCH + LDSPAD] = (ushort(*)[HCH + LDSPAD])(smem + 17408);
    float (*Cs)[132] = (float(*)[132])(smem + 17408);

    const int t = threadIdx.x;
    const int mb = blockIdx.x * 64;

    __shared__ float invl_s[8];
    if (t < 8) invl_s[t] = 1.0f / head_l[t];
    __syncthreads();

    // stage A: 64 rows x 32 uint2 (128 bf16 channels each row)
#pragma unroll
    for (int i = 0; i < 8; i++) {
        int p = t + i * 256;
        int row = p >> 5, cu2 = p & 31;
        int g = mb + row;
        uint2 a = make_uint2(0, 0);
        if (g < M) a = *(const uint2*)(A + (size_t)g * HCH + cu2 * 4);
        float invl = invl_s[cu2 >> 2];      // 4 ch per uint2, 16 per head
        float f0 = bflo(a.x) * invl, f1 = bfhi(a.x) * invl;
        float f2 = bflo(a.y) * invl, f3 = bfhi(a.y) * invl;
        uint lo = (uint)f2bf(f0) | ((uint)f2bf(f1) << 16);
        uint hi = (uint)f2bf(f2) | ((uint)f2bf(f3) << 16);
        *(uint2*)(&As[row][cu2 * 4]) = make_uint2(lo, hi);
    }
#pragma unroll
    for (int i = 0; i < 16; i++) {
        int p = t + i * 256;
        int n = p & 127, k4 = p >> 7;
        float w0 = W[(size_t)(k4 * 4 + 0) * HCH + n];
        float w1 = W[(size_t)(k4 * 4 + 1) * HCH + n];
        float w2 = W[(size_t)(k4 * 4 + 2) * HCH + n];
        float w3 = W[(size_t)(k4 * 4 + 3) * HCH + n];
        uint lo = (uint)f2bf(w0) | ((uint)f2bf(w1) << 16);
        uint hi = (uint)f2bf(w2) | ((uint)f2bf(w3) << 16);
        *(uint2*)(&Wt[n][k4 * 4]) = make_uint2(lo, hi);
    }
    __syncthreads();

    const int lane = t & 63;
    const int w = t >> 6;
    const int m_l = lane & 15;
    const int q_l = lane >> 4;

    floatx4 acc[8];
#pragma unroll
    for (int tl = 0; tl < 8; tl++) acc[tl] = (floatx4){0.f, 0.f, 0.f, 0.f};

#pragma unroll
    for (int ks = 0; ks < HCH; ks += 32) {
        short8 af = *(const short8*)(&As[w * 16 + m_l][ks + q_l * 8]);
#pragma unroll
        for (int tl = 0; tl < 8; tl++) {
            short8 bf = *(const short8*)(&Wt[tl * 16 + m_l][ks + q_l * 8]);
            acc[tl] = __builtin_amdgcn_mfma_f32_16x16x32_bf16(af, bf, acc[tl], 0, 0, 0);
        }
    }
    __syncthreads();

#pragma unroll
    for (int tl = 0; tl < 8; tl++)
#pragma unroll
        for (int r = 0; r < 4; r++)
            Cs[w * 16 + q_l * 4 + r][tl * 16 + m_l] = acc[tl][r];
    __syncthreads();

#pragma unroll
    for (int i = 0; i < 8; i++) {
        int p = t + i * 256;
        int row = p >> 5, c4 = p & 31;
        int g = mb + row;
        if (g >= M) continue;
        float4 b4 = *(const float4*)(bias + c4 * 4);
        float4 r4 = *(const float4*)(res + (size_t)g * HCH + c4 * 4);
        float4 o;
        o.x = Cs[row][c4 * 4 + 0] + b4.x + r4.x;
        o.y = Cs[row][c4 * 4 + 1] + b4.y + r4.y;
        o.z = Cs[row][c4 * 4 + 2] + b4.z + r4.z;
        o.w = Cs[row][c4 * 4 + 3] + b4.w + r4.w;
        *(float4*)(C + (size_t)g * HCH + c4 * 4) = o;
    }
}

// ================= two-pass bucketed counting sort by dst =================
constexpr int BSHIFT = 8;
constexpr int NBUCK  = ((N_NODES - 1) >> BSHIFT) + 1;   // 391
constexpr int S1_GRID = 256;
constexpr int S1_CH   = (E_EDGES + S1_GRID - 1) / S1_GRID;  // 6250
constexpr int S2_CAP  = 6144;

__global__ __launch_bounds__(256) void bucket_hist(
    const int* __restrict__ dst, int* __restrict__ bucket_total)
{
    __shared__ int cnt[NBUCK];
    const int t = threadIdx.x;
    for (int b = t; b < NBUCK; b += 256) cnt[b] = 0;
    __syncthreads();
    const int e0 = blockIdx.x * S1_CH;
    const int n = min(S1_CH, E_EDGES - e0);
    for (int i = t; i < n; i += 256)
        atomicAdd(&cnt[dst[e0 + i] >> BSHIFT], 1);
    __syncthreads();
    for (int b = t; b < NBUCK; b += 256)
        if (cnt[b]) atomicAdd(&bucket_total[b], cnt[b]);
}

__global__ __launch_bounds__(512) void bucket_scan(
    const int* __restrict__ bucket_total, int* __restrict__ bucket_start,
    int* __restrict__ bucket_cursor, int* __restrict__ offsets)
{
    __shared__ int s[512];
    const int t = threadIdx.x;
    int v = (t < NBUCK) ? bucket_total[t] : 0;
    s[t] = v;
    __syncthreads();
    for (int off = 1; off < 512; off <<= 1) {
        int a = (t >= off) ? s[t - off] : 0;
        __syncthreads();
        s[t] += a;
        __syncthreads();
    }
    int excl = s[t] - v;
    if (t < NBUCK) { bucket_start[t] = excl; bucket_cursor[t] = excl; }
    if (t == 0) { bucket_start[NBUCK] = E_EDGES; offsets[N_NODES] = E_EDGES; }
}

__global__ __launch_bounds__(256) void sort_scatter1(
    const int* __restrict__ src, const int* __restrict__ dst,
    int* __restrict__ bucket_cursor, int2* __restrict__ tmp)
{
    __shared__ int ls[S1_CH];
    __shared__ int ld[S1_CH];
    __shared__ int cnt[NBUCK];
    const int t = threadIdx.x;
    for (int b = t; b < NBUCK; b += 256) cnt[b] = 0;
    __syncthreads();
    const int e0 = blockIdx.x * S1_CH;
    const int n = min(S1_CH, E_EDGES - e0);
    for (int i = t; i < n; i += 256) {
        int d = dst[e0 + i];
        ls[i] = src[e0 + i];
        ld[i] = d;
        atomicAdd(&cnt[d >> BSHIFT], 1);
    }
    __syncthreads();
    for (int b = t; b < NBUCK; b += 256) {
        int c = cnt[b];
        cnt[b] = c ? atomicAdd(&bucket_cursor[b], c) : 0;
    }
    __syncthreads();
    for (int i = t; i < n; i += 256) {
        int d = ld[i];
        int pos = atomicAdd(&cnt[d >> BSHIFT], 1);
        tmp[pos] = make_int2(ls[i], d);
    }
}

// writes src-only permuted list + per-node offsets
__global__ __launch_bounds__(256) void sort_scatter2(
    const int2* __restrict__ tmp, const int* __restrict__ bucket_start,
    int* __restrict__ srcs, int* __restrict__ offsets)
{
    __shared__ int2 le[S2_CAP];
    __shared__ int cnt[256];
    __shared__ int s[256];
    __shared__ int cur[256];
    const int t = threadIdx.x;
    const int b = blockIdx.x;
    const int bstart = bucket_start[b];
    const int n = bucket_start[b + 1] - bstart;
    cnt[t] = 0;
    __syncthreads();
    for (int i = t; i < n; i += 256) {
        int2 e = tmp[bstart + i];
        if (i < S2_CAP) le[i] = e;
        atomicAdd(&cnt[e.y & 255], 1);
    }
    __syncthreads();
    int v = cnt[t];
    s[t] = v;
    __syncthreads();
    for (int off = 1; off < 256; off <<= 1) {
        int a = (t >= off) ? s[t - off] : 0;
        __syncthreads();
        s[t] += a;
        __syncthreads();
    }
    int excl = s[t] - v;
    int node = (b << BSHIFT) + t;
    if (node < N_NODES) offsets[node] = bstart + excl;
    cur[t] = excl;
    __syncthreads();
    for (int i = t; i < n; i += 256) {
        int2 e = (i < S2_CAP) ? le[i] : tmp[bstart + i];
        int pos = bstart + atomicAdd(&cur[e.y & 255], 1);
        srcs[pos] = e.x;
    }
}

// ============ fused scores+gather: one wave per dst node ============
// per edge: s = q[d].k[src]/4 (fp8 k), w = exp(s), acc += w * v[src] (fp8 v)
__global__ __launch_bounds__(256) void edge_fused(
    const ushort* __restrict__ q, const uchar* __restrict__ kv,
    const int* __restrict__ srcs, const int* __restrict__ offsets,
    float* __restrict__ head_l, ushort* __restrict__ attended)
{
    const int t = threadIdx.x;
    const int lane = t & 63;
    const int d = blockIdx.x * 4 + (t >> 6);   // grid = N/4 exactly
    float lsum = 0.f;

    uint qu = *(const uint*)(q + (size_t)d * HCH + lane * 2);
    const float q0 = bflo(qu), q1 = bfhi(qu);
    const int start = offsets[d];
    const int end   = offsets[d + 1];
    float a0 = 0.f, a1 = 0.f;

    int i = start;
    for (; i + 3 < end; i += 4) {
        int s0 = srcs[i], s1 = srcs[i + 1], s2 = srcs[i + 2], s3 = srcs[i + 3];
        const uchar* r0 = kv + (size_t)s0 * 256 + lane * 2;
        const uchar* r1 = kv + (size_t)s1 * 256 + lane * 2;
        const uchar* r2 = kv + (size_t)s2 * 256 + lane * 2;
        const uchar* r3 = kv + (size_t)s3 * 256 + lane * 2;
        ushort k0 = *(const ushort*)r0, k1 = *(const ushort*)r1;
        ushort k2 = *(const ushort*)r2, k3 = *(const ushort*)r3;
        ushort v0 = *(const ushort*)(r0 + 128), v1 = *(const ushort*)(r1 + 128);
        ushort v2 = *(const ushort*)(r2 + 128), v3 = *(const ushort*)(r3 + 128);
        floatx2 kf0 = __builtin_amdgcn_cvt_pk_f32_fp8((int)k0, false);
        floatx2 kf1 = __builtin_amdgcn_cvt_pk_f32_fp8((int)k1, false);
        floatx2 kf2 = __builtin_amdgcn_cvt_pk_f32_fp8((int)k2, false);
        floatx2 kf3 = __builtin_amdgcn_cvt_pk_f32_fp8((int)k3, false);
        float p0 = q0 * kf0.x + q1 * kf0.y;
        float p1 = q0 * kf1.x + q1 * kf1.y;
        float p2 = q0 * kf2.x + q1 * kf2.y;
        float p3 = q0 * kf3.x + q1 * kf3.y;
        p0 += __shfl_xor(p0, 1, 64); p1 += __shfl_xor(p1, 1, 64);
        p2 += __shfl_xor(p2, 1, 64); p3 += __shfl_xor(p3, 1, 64);
        p0 += __shfl_xor(p0, 2, 64); p1 += __shfl_xor(p1, 2, 64);
        p2 += __shfl_xor(p2, 2, 64); p3 += __shfl_xor(p3, 2, 64);
        p0 += __shfl_xor(p0, 4, 64); p1 += __shfl_xor(p1, 4, 64);
        p2 += __shfl_xor(p2, 4, 64); p3 += __shfl_xor(p3, 4, 64);
        float w0 = __expf(p0 * 0.25f), w1 = __expf(p1 * 0.25f);
        float w2 = __expf(p2 * 0.25f), w3 = __expf(p3 * 0.25f);
        floatx2 vf0 = __builtin_amdgcn_cvt_pk_f32_fp8((int)v0, false);
        floatx2 vf1 = __builtin_amdgcn_cvt_pk_f32_fp8((int)v1, false);
        floatx2 vf2 = __builtin_amdgcn_cvt_pk_f32_fp8((int)v2, false);
        floatx2 vf3 = __builtin_amdgcn_cvt_pk_f32_fp8((int)v3, false);
        a0 += w0 * vf0.x + w1 * vf1.x + w2 * vf2.x + w3 * vf3.x;
        a1 += w0 * vf0.y + w1 * vf1.y + w2 * vf2.y + w3 * vf3.y;
        lsum += w0 + w1 + w2 + w3;
    }
    for (; i < end; i++) {
        int s0 = srcs[i];
        const uchar* r0 = kv + (size_t)s0 * 256 + lane * 2;
        ushort k0 = *(const ushort*)r0;
        ushort v0 = *(const ushort*)(r0 + 128);
        floatx2 kf0 = __builtin_amdgcn_cvt_pk_f32_fp8((int)k0, false);
        float p0 = q0 * kf0.x + q1 * kf0.y;
        p0 += __shfl_xor(p0, 1, 64);
        p0 += __shfl_xor(p0, 2, 64);
        p0 += __shfl_xor(p0, 4, 64);
        float w0 = __expf(p0 * 0.25f);
        floatx2 vf0 = __builtin_amdgcn_cvt_pk_f32_fp8((int)v0, false);
        a0 += w0 * vf0.x;
        a1 += w0 * vf0.y;
        lsum += w0;
    }
    *(uint*)(attended + (size_t)d * HCH + lane * 2) =
        (uint)f2bf(a0) | ((uint)f2bf(a1) << 16);

    // per-block L per head: one representative lane (lane h*8) per wave
    __shared__ float sl[256];
    sl[t] = lsum;
    __syncthreads();
    if (t < 8) {
        float L = sl[t * 8] + sl[64 + t * 8] + sl[128 + t * 8] + sl[192 + t * 8];
        atomicAdd(&head_l[t], L);
    }
}

extern "C" void kernel_launch(void* const* d_in, const int* in_sizes, int n_in,
                              void* d_out, int out_size, void* d_ws, size_t ws_size,
                              hipStream_t stream)
{
    const float* x  = (const float*)d_in[0];
    const int* eidx = (const int*)d_in[1];
    const float* Wq = (const float*)d_in[2];
    const float* bq = (const float*)d_in[3];
    const float* Wk = (const float*)d_in[4];
    const float* bk = (const float*)d_in[5];
    const float* Wv = (const float*)d_in[6];
    const float* bv = (const float*)d_in[7];
    const float* Wo = (const float*)d_in[8];
    const float* bo = (const float*)d_in[9];
    float* out = (float*)d_out;

    char* ws = (char*)d_ws;
    constexpr size_t SZ_BF  = (size_t)N_NODES * HCH * 2;       // 25.6 MB
    constexpr size_t SZ_KV  = (size_t)N_NODES * 256;           // 25.6 MB (fp8 k|v)
    constexpr size_t SZ_PE  = (size_t)E_EDGES * sizeof(int2);  // 12.8 MB
    constexpr size_t SZ_SRC = (size_t)E_EDGES * sizeof(int);   // 6.4 MB
    size_t off = 0;
    ushort* q        = (ushort*)(ws + off); off += SZ_BF;
    uchar*  kv       = (uchar*)(ws + off);  off += SZ_KV;
    ushort* attended = (ushort*)(ws + off); off += SZ_BF;
    int2*   tmp      = (int2*)(ws + off);   off += SZ_PE;
    int*    srcs     = (int*)(ws + off);    off += SZ_SRC;
    int*    offsets  = (int*)(ws + off);    off += ((size_t)N_NODES + 1) * 4 + 4;
    int*    bucket_total  = (int*)(ws + off); off += (NBUCK + 1) * 4;
    float*  head_l   = (float*)(ws + off);  off += 32;   // memset together w/ bucket_total
    int*    bucket_start  = (int*)(ws + off); off += (NBUCK + 1) * 4;
    int*    bucket_cursor = (int*)(ws + off); off += (NBUCK + 1) * 4;
    const int* src = eidx;
    const int* dst = eidx + E_EDGES;

    dim3 blk(256);
    const int gblocks = (N_NODES + 63) / 64;

    gemm_qkv<<<dim3(gblocks, 3), blk, 0, stream>>>(x, Wq, Wk, Wv, bq, bk, bv, q, kv, N_NODES);

    hipMemsetAsync(bucket_total, 0, (NBUCK + 1) * 4 + 32, stream);  // also zeroes head_l
    bucket_hist<<<S1_GRID, blk, 0, stream>>>(dst, bucket_total);
    bucket_scan<<<1, 512, 0, stream>>>(bucket_total, bucket_start, bucket_cursor, offsets);
    sort_scatter1<<<S1_GRID, blk, 0, stream>>>(src, dst, bucket_cursor, tmp);
    sort_scatter2<<<NBUCK, blk, 0, stream>>>(tmp, bucket_start, srcs, offsets);

    edge_fused<<<N_NODES / 4, blk, 0, stream>>>(q, kv, srcs, offsets, head_l, attended);

    gemm_out<<<gblocks, blk, 0, stream>>>(attended, Wo, bo, x, head_l, out, N_NODES);
}